// Round 6
// baseline (417.136 us; speedup 1.0000x reference)
//
#include <hip/hip_runtime.h>

typedef __attribute__((ext_vector_type(8))) short short8;
typedef __attribute__((ext_vector_type(4))) float f32x4;
typedef __attribute__((ext_vector_type(2))) float f32x2;

#define TSTEPS 50
#define HOR    50

__device__ __forceinline__ float frcp(float x) { return __builtin_amdgcn_rcpf(x); }
__device__ __forceinline__ float sigmoidf(float x) { return frcp(1.f + __expf(-x)); }
__device__ __forceinline__ float tanh_fast(float x) {
  float ax = fabsf(x);
  float e  = __expf(-2.f * ax);
  float r  = (1.f - e) * frcp(1.f + e);
  return copysignf(r, x);
}
// packed f32->bf16 RNE (no builtin on gfx950 -> inline asm)
__device__ __forceinline__ unsigned cvt_pk_bf16(float a, float b) {
  unsigned r;
  asm("v_cvt_pk_bf16_f32 %0, %1, %2" : "=v"(r) : "v"(a), "v"(b));
  return r;
}
union S8U { short8 s; unsigned u[4]; };

// 8 floats -> bf16 hi fragment + exact-residual lo fragment
__device__ __forceinline__ void split8(const float* f, short8& hi, short8& lo) {
  S8U h, l;
  #pragma unroll
  for (int e = 0; e < 4; ++e) {
    float a = f[2 * e], b = f[2 * e + 1];
    unsigned ph = cvt_pk_bf16(a, b);
    float ah = __uint_as_float(ph << 16);
    float bh = __uint_as_float(ph & 0xFFFF0000u);
    h.u[e] = ph;
    l.u[e] = cvt_pk_bf16(a - ah, b - bh);
  }
  hi = h.s; lo = l.s;
}

__global__ __launch_bounds__(256, 4)
void traj_lstm_mfma4(const float* __restrict__ hist,   // (B, 50, 2)
                     const float* __restrict__ W_ih,   // (256, 2)
                     const float* __restrict__ W_hh,   // (256, 64)
                     const float* __restrict__ b_ih,   // (256)
                     const float* __restrict__ b_hh,   // (256)
                     const float* __restrict__ W_dec,  // (2, 64)
                     const float* __restrict__ b_dec,  // (2)
                     float* __restrict__ out)          // (B, 50, 2)
{
  // one 16-batch group per block, 4 waves quarter-split over hidden dim
  __shared__ float hsh[2][16][68];   // [buf][batch][hidden j] (stride 68: 2-way=free)
  __shared__ float wdl[2][64];       // W_dec rows

  const int tid  = threadIdx.x;
  const int q    = tid >> 6;    // wave's hidden quarter: j in [16q, 16q+16)
  const int lane = tid & 63;
  const int col  = lane & 15;   // MFMA col (gate n / batch m)
  const int g    = lane >> 4;   // lane group = k-slice / batch-row group
  const int batch0 = blockIdx.x * 16;

  // ---- W_hh fragments for this wave's 4 gate-tiles (hi/lo bf16), persistent ----
  // gate row = gt*64 + 16q + col ; B[k][n]: n=col, k = kq*32 + 8g + e
  short8 wbhi[4][2], wblo[4][2];
  #pragma unroll
  for (int gt = 0; gt < 4; ++gt) {
    const int row = gt * 64 + q * 16 + col;
    #pragma unroll
    for (int kq = 0; kq < 2; ++kq) {
      float f[8];
      #pragma unroll
      for (int e = 0; e < 8; ++e) f[e] = W_hh[row * 64 + kq * 32 + g * 8 + e];
      split8(f, wbhi[gt][kq], wblo[gt][kq]);
    }
  }

  // ---- per-cell constants (4 cells/lane: batches 4g+r, hidden j = 16q+col) ----
  float bias[4], wih0[4], wih1[4];
  #pragma unroll
  for (int gt = 0; gt < 4; ++gt) {
    const int row = gt * 64 + q * 16 + col;
    bias[gt] = b_ih[row] + b_hh[row];
    wih0[gt] = W_ih[row * 2];
    wih1[gt] = W_ih[row * 2 + 1];
  }
  const float bd0 = b_dec[0], bd1 = b_dec[1];

  if (tid < 128) wdl[tid >> 6][tid & 63] = W_dec[tid];
  for (int i = tid; i < 16 * 68; i += 256) ((float*)hsh[0])[i] = 0.f;  // h0 = 0

  float cst[4] = {0.f, 0.f, 0.f, 0.f};
  float x0[4], x1[4];   // encode: from hist; decode: feedback (set by decoder)

  __syncthreads();

  for (int s = 0; s < TSTEPS + HOR; ++s) {
    const int par = s & 1;

    // ---- A fragments from hsh[par]: A[m=col][k=kq*32+8g+e], hi/lo ----
    short8 ahi[2], alo[2];
    #pragma unroll
    for (int kq = 0; kq < 2; ++kq) {
      float hf[8];
      *(f32x4*)&hf[0] = *(const f32x4*)&hsh[par][col][kq * 32 + g * 8];
      *(f32x4*)&hf[4] = *(const f32x4*)&hsh[par][col][kq * 32 + g * 8 + 4];
      split8(hf, ahi[kq], alo[kq]);
    }

    // ---- x for this step ----
    if (s <= TSTEPS) {
      const int ss = (s < TSTEPS) ? s : (TSTEPS - 1);
      #pragma unroll
      for (int r = 0; r < 4; ++r) {
        f32x2 xv = *(const f32x2*)&hist[(size_t)(batch0 + 4 * g + r) * 100 + ss * 2];
        x0[r] = xv.x; x1[r] = xv.y;
      }
    }
    // else: x0/x1 already hold decoder feedback from previous iteration

    // ---- 24 MFMAs: 4 gate-tiles, 3-term bf16 split ----
    f32x4 acc[4];
    #pragma unroll
    for (int gt = 0; gt < 4; ++gt) {
      f32x4 a = {0.f, 0.f, 0.f, 0.f};
      a = __builtin_amdgcn_mfma_f32_16x16x32_bf16(ahi[0], wbhi[gt][0], a, 0, 0, 0);
      a = __builtin_amdgcn_mfma_f32_16x16x32_bf16(ahi[1], wbhi[gt][1], a, 0, 0, 0);
      a = __builtin_amdgcn_mfma_f32_16x16x32_bf16(alo[0], wbhi[gt][0], a, 0, 0, 0);
      a = __builtin_amdgcn_mfma_f32_16x16x32_bf16(alo[1], wbhi[gt][1], a, 0, 0, 0);
      a = __builtin_amdgcn_mfma_f32_16x16x32_bf16(ahi[0], wblo[gt][0], a, 0, 0, 0);
      a = __builtin_amdgcn_mfma_f32_16x16x32_bf16(ahi[1], wblo[gt][1], a, 0, 0, 0);
      acc[gt] = a;
    }

    // ---- LSTM cell: batch = 4g+r, hidden j = 16q+col ----
    #pragma unroll
    for (int r = 0; r < 4; ++r) {
      float gi = acc[0][r] + bias[0] + x0[r] * wih0[0] + x1[r] * wih1[0];
      float gf = acc[1][r] + bias[1] + x0[r] * wih0[1] + x1[r] * wih1[1];
      float gg = acc[2][r] + bias[2] + x0[r] * wih0[2] + x1[r] * wih1[2];
      float go = acc[3][r] + bias[3] + x0[r] * wih0[3] + x1[r] * wih1[3];
      float si = sigmoidf(gi);
      float sf = sigmoidf(gf);
      float tg = tanh_fast(gg);
      float so = sigmoidf(go);
      float cn = fmaf(sf, cst[r], si * tg);
      cst[r] = cn;
      hsh[par ^ 1][4 * g + r][q * 16 + col] = so * tanh_fast(cn);
    }
    __syncthreads();   // the only barrier per step

    // ---- decoder head: every wave computes BOTH features (barrier-free) ----
    if (s >= TSTEPS) {
      const float* hr = &hsh[par ^ 1][col][g * 16];  // batch=col, k-slice=g
      float p0 = 0.f, p1 = 0.f;
      #pragma unroll
      for (int e4 = 0; e4 < 4; ++e4) {
        f32x4 hv = *(const f32x4*)&hr[e4 * 4];
        f32x4 w0 = *(const f32x4*)&wdl[0][g * 16 + e4 * 4];
        f32x4 w1 = *(const f32x4*)&wdl[1][g * 16 + e4 * 4];
        p0 += hv.x * w0.x + hv.y * w0.y + hv.z * w0.z + hv.w * w0.w;
        p1 += hv.x * w1.x + hv.y * w1.y + hv.z * w1.z + hv.w * w1.w;
      }
      p0 += __shfl_xor(p0, 16); p0 += __shfl_xor(p0, 32);
      p1 += __shfl_xor(p1, 16); p1 += __shfl_xor(p1, 32);
      p0 += bd0; p1 += bd1;     // every lane: features of batch 'col'

      if (q == 0 && g == 0) {
        f32x2 o2 = { p0, p1 };
        *(f32x2*)&out[(size_t)(batch0 + col) * 100 + (size_t)(s - TSTEPS) * 2] = o2;
      }
      // feedback x for next step: batch 4g+r lives in lanes with col==4g+r
      #pragma unroll
      for (int r = 0; r < 4; ++r) {
        x0[r] = __shfl(p0, 4 * g + r);
        x1[r] = __shfl(p1, 4 * g + r);
      }
    }
  }
}

extern "C" void kernel_launch(void* const* d_in, const int* in_sizes, int n_in,
                              void* d_out, int out_size, void* d_ws, size_t ws_size,
                              hipStream_t stream) {
  (void)in_sizes; (void)n_in; (void)ws_size; (void)d_ws; (void)out_size;
  const float* hist  = (const float*)d_in[0];
  const float* W_ih  = (const float*)d_in[1];
  const float* W_hh  = (const float*)d_in[2];
  const float* b_ih  = (const float*)d_in[3];
  const float* b_hh  = (const float*)d_in[4];
  const float* W_dec = (const float*)d_in[5];
  const float* b_dec = (const float*)d_in[6];
  float* out = (float*)d_out;

  dim3 grid(16384 / 16);   // 1024 blocks: 16 batches, 4 quarter-split waves each
  dim3 block(256);
  traj_lstm_mfma4<<<grid, block, 0, stream>>>(hist, W_ih, W_hh, b_ih, b_hh,
                                              W_dec, b_dec, out);
}

// Round 7
// 348.504 us; speedup vs baseline: 1.1969x; 1.1969x over previous
//
#include <hip/hip_runtime.h>

typedef __attribute__((ext_vector_type(8))) short short8;
typedef __attribute__((ext_vector_type(4))) float f32x4;
typedef __attribute__((ext_vector_type(2))) float f32x2;

#define TSTEPS 50
#define HOR    50

__device__ __forceinline__ float frcp(float x) { return __builtin_amdgcn_rcpf(x); }
__device__ __forceinline__ float sigmoidf(float x) { return frcp(1.f + __expf(-x)); }
__device__ __forceinline__ float tanh_fast(float x) {
  float ax = fabsf(x);
  float e  = __expf(-2.f * ax);
  float r  = (1.f - e) * frcp(1.f + e);
  return copysignf(r, x);
}
// packed f32->bf16 RNE (no builtin on gfx950 -> inline asm); low 16 = src0
__device__ __forceinline__ unsigned cvt_pk_bf16(float a, float b) {
  unsigned r;
  asm("v_cvt_pk_bf16_f32 %0, %1, %2" : "=v"(r) : "v"(a), "v"(b));
  return r;
}
__device__ __forceinline__ float bf2f(unsigned short b) {
  return __uint_as_float(((unsigned)b) << 16);
}
union S8U { short8 s; unsigned u[4]; };

__global__ __launch_bounds__(512, 4)
void traj_lstm_q(const float* __restrict__ hist,   // (B, 50, 2)
                 const float* __restrict__ W_ih,   // (256, 2)
                 const float* __restrict__ W_hh,   // (256, 64)
                 const float* __restrict__ b_ih,   // (256)
                 const float* __restrict__ b_hh,   // (256)
                 const float* __restrict__ W_dec,  // (2, 64)
                 const float* __restrict__ b_dec,  // (2)
                 float* __restrict__ out)          // (B, 50, 2)
{
  // W_lo residuals (bf16), padded rows: row stride 144 B (16B-mult, 2-way banks)
  __shared__ unsigned short wloL[256][72];          // 36.9 KB
  // h exchange, bf16 hi/lo, double-buffered per pair: [buf][pair][batch][j]
  __shared__ unsigned short hshH[2][2][16][72];     // 9.2 KB
  __shared__ unsigned short hshL[2][2][16][72];     // 9.2 KB
  __shared__ float wdl[2][64];                      // 0.5 KB

  const int tid  = threadIdx.x;
  const int wv   = tid >> 6;
  const int lane = tid & 63;
  const int pr   = wv >> 2;     // pair (16-batch group) 0/1
  const int q    = wv & 3;      // hidden quarter: j in [16q, 16q+16)
  const int col  = lane & 15;
  const int g    = lane >> 4;
  const int batch0 = blockIdx.x * 32 + pr * 16;

  // ---- one-time: W_lo residual table into LDS (coalesced, conflict-light) ----
  for (int idx = tid; idx < 256 * 64; idx += 512) {
    float wf = W_hh[idx];
    unsigned short hi = (unsigned short)(cvt_pk_bf16(wf, wf) & 0xFFFFu);
    float res = wf - bf2f(hi);
    wloL[idx >> 6][idx & 63] = (unsigned short)(cvt_pk_bf16(res, res) & 0xFFFFu);
  }
  if (tid < 128) wdl[tid >> 6][tid & 63] = W_dec[tid];
  for (int idx = tid; idx < 2 * 2 * 16 * 72; idx += 512) {
    ((unsigned short*)hshH)[idx] = 0;   // bf16 zero
    ((unsigned short*)hshL)[idx] = 0;
  }

  // ---- W_hi resident fragments: 8 short8 = 32 VGPR ----
  // tile gt: gate rows gt*64 + 16q + col; B[k][n]: n=col, k = kq*32 + 8g + e
  short8 wbhi[4][2];
  #pragma unroll
  for (int gt = 0; gt < 4; ++gt) {
    const int row = gt * 64 + q * 16 + col;
    #pragma unroll
    for (int kq = 0; kq < 2; ++kq) {
      const float* wr = &W_hh[row * 64 + kq * 32 + g * 8];
      S8U h8;
      #pragma unroll
      for (int e4 = 0; e4 < 4; ++e4)
        h8.u[e4] = cvt_pk_bf16(wr[2 * e4], wr[2 * e4 + 1]);
      wbhi[gt][kq] = h8.s;
    }
  }

  // ---- per-cell constants (4 cells/lane: batch 4g+r, j = 16q+col) ----
  float bias[4], wih0[4], wih1[4];
  #pragma unroll
  for (int gt = 0; gt < 4; ++gt) {
    const int row = gt * 64 + q * 16 + col;
    bias[gt] = b_ih[row] + b_hh[row];
    wih0[gt] = W_ih[row * 2];
    wih1[gt] = W_ih[row * 2 + 1];
  }
  const float bd0 = b_dec[0], bd1 = b_dec[1];

  float cst[4] = {0.f, 0.f, 0.f, 0.f};
  float x0[4], x1[4];

  __syncthreads();

  for (int s = 0; s < TSTEPS + HOR; ++s) {
    const int par = s & 1;

    // ---- A fragments: direct bf16 hi/lo reads (no per-step split VALU) ----
    short8 ahi[2], alo[2];
    #pragma unroll
    for (int kq = 0; kq < 2; ++kq) {
      ahi[kq] = *(const short8*)&hshH[par][pr][col][kq * 32 + g * 8];
      alo[kq] = *(const short8*)&hshL[par][pr][col][kq * 32 + g * 8];
    }

    // ---- x for this step ----
    if (s <= TSTEPS) {
      const int ss = (s < TSTEPS) ? s : (TSTEPS - 1);
      #pragma unroll
      for (int r = 0; r < 4; ++r) {
        f32x2 xv = *(const f32x2*)&hist[(size_t)(batch0 + 4 * g + r) * 100 + ss * 2];
        x0[r] = xv.x; x1[r] = xv.y;
      }
    }
    // else: x0/x1 hold decoder feedback

    // ---- 24 MFMAs: W_hi from regs, W_lo from LDS ----
    f32x4 acc[4];
    #pragma unroll
    for (int gt = 0; gt < 4; ++gt) {
      const int row = gt * 64 + q * 16 + col;
      short8 wlo0 = *(const short8*)&wloL[row][g * 8];
      short8 wlo1 = *(const short8*)&wloL[row][32 + g * 8];
      f32x4 a = {0.f, 0.f, 0.f, 0.f};
      a = __builtin_amdgcn_mfma_f32_16x16x32_bf16(ahi[0], wbhi[gt][0], a, 0, 0, 0);
      a = __builtin_amdgcn_mfma_f32_16x16x32_bf16(ahi[1], wbhi[gt][1], a, 0, 0, 0);
      a = __builtin_amdgcn_mfma_f32_16x16x32_bf16(alo[0], wbhi[gt][0], a, 0, 0, 0);
      a = __builtin_amdgcn_mfma_f32_16x16x32_bf16(alo[1], wbhi[gt][1], a, 0, 0, 0);
      a = __builtin_amdgcn_mfma_f32_16x16x32_bf16(ahi[0], wlo0, a, 0, 0, 0);
      a = __builtin_amdgcn_mfma_f32_16x16x32_bf16(ahi[1], wlo1, a, 0, 0, 0);
      acc[gt] = a;
    }

    // ---- LSTM cell: batch 4g+r, hidden j = 16q+col; split h at producer ----
    #pragma unroll
    for (int r = 0; r < 4; ++r) {
      float gi = acc[0][r] + bias[0] + x0[r] * wih0[0] + x1[r] * wih1[0];
      float gf = acc[1][r] + bias[1] + x0[r] * wih0[1] + x1[r] * wih1[1];
      float gg = acc[2][r] + bias[2] + x0[r] * wih0[2] + x1[r] * wih1[2];
      float go = acc[3][r] + bias[3] + x0[r] * wih0[3] + x1[r] * wih1[3];
      float si = sigmoidf(gi);
      float sf = sigmoidf(gf);
      float tg = tanh_fast(gg);
      float so = sigmoidf(go);
      float cn = fmaf(sf, cst[r], si * tg);
      cst[r] = cn;
      float hv = so * tanh_fast(cn);
      unsigned short hhi = (unsigned short)(cvt_pk_bf16(hv, hv) & 0xFFFFu);
      float res = hv - bf2f(hhi);
      unsigned short hlo = (unsigned short)(cvt_pk_bf16(res, res) & 0xFFFFu);
      hshH[par ^ 1][pr][4 * g + r][q * 16 + col] = hhi;
      hshL[par ^ 1][pr][4 * g + r][q * 16 + col] = hlo;
    }
    __syncthreads();   // the only barrier per step

    // ---- decoder: every wave computes BOTH features (barrier-free) ----
    if (s >= TSTEPS) {
      short8 hh0 = *(const short8*)&hshH[par ^ 1][pr][col][g * 16];
      short8 hh1 = *(const short8*)&hshH[par ^ 1][pr][col][g * 16 + 8];
      short8 hl0 = *(const short8*)&hshL[par ^ 1][pr][col][g * 16];
      short8 hl1 = *(const short8*)&hshL[par ^ 1][pr][col][g * 16 + 8];
      float p0 = 0.f, p1 = 0.f;
      #pragma unroll
      for (int e = 0; e < 8; ++e) {
        float hv0 = bf2f((unsigned short)hh0[e]) + bf2f((unsigned short)hl0[e]);
        float hv1 = bf2f((unsigned short)hh1[e]) + bf2f((unsigned short)hl1[e]);
        p0 = fmaf(hv0, wdl[0][g * 16 + e], p0);
        p0 = fmaf(hv1, wdl[0][g * 16 + 8 + e], p0);
        p1 = fmaf(hv0, wdl[1][g * 16 + e], p1);
        p1 = fmaf(hv1, wdl[1][g * 16 + 8 + e], p1);
      }
      p0 += __shfl_xor(p0, 16); p0 += __shfl_xor(p0, 32);
      p1 += __shfl_xor(p1, 16); p1 += __shfl_xor(p1, 32);
      p0 += bd0; p1 += bd1;     // lane L: features of batch (L & 15)

      if (q == 0 && g == 0) {
        f32x2 o2 = { p0, p1 };
        *(f32x2*)&out[(size_t)(batch0 + col) * 100 + (size_t)(s - TSTEPS) * 2] = o2;
      }
      // feedback x for next step: batch 4g+r value lives in lane 4g+r
      #pragma unroll
      for (int r = 0; r < 4; ++r) {
        x0[r] = __shfl(p0, 4 * g + r);
        x1[r] = __shfl(p1, 4 * g + r);
      }
    }
  }
}

extern "C" void kernel_launch(void* const* d_in, const int* in_sizes, int n_in,
                              void* d_out, int out_size, void* d_ws, size_t ws_size,
                              hipStream_t stream) {
  (void)in_sizes; (void)n_in; (void)ws_size; (void)d_ws; (void)out_size;
  const float* hist  = (const float*)d_in[0];
  const float* W_ih  = (const float*)d_in[1];
  const float* W_hh  = (const float*)d_in[2];
  const float* b_ih  = (const float*)d_in[3];
  const float* b_hh  = (const float*)d_in[4];
  const float* W_dec = (const float*)d_in[5];
  const float* b_dec = (const float*)d_in[6];
  float* out = (float*)d_out;

  dim3 grid(16384 / 32);   // 512 blocks: 2 pairs x 4 quarter-split waves
  dim3 block(512);
  traj_lstm_q<<<grid, block, 0, stream>>>(hist, W_ih, W_hh, b_ih, b_hh,
                                          W_dec, b_dec, out);
}